// Round 2
// baseline (475.404 us; speedup 1.0000x reference)
//
#include <hip/hip_runtime.h>

// Problem: B=8, S=1024, V=8192, D=256. out[b,s,:] = (x[b,s,:] @ E)*16 + pos[s,:]*any(x[b,s,:])
// GEMM M=8192 K=8192 N=256, A=x (0/1 int32), B=emb. HBM-bound on streaming x (256 MB).
// R2: barrier-free gemm — direct per-wave A fragment loads (no LDS), in-register int->bf16
//     packing, fragment-major B table, KSPLIT=8.

#define M_TOT 8192
#define K_TOT 8192
#define D_DIM 256
#define KSPLIT 8
#define KCHUNK (K_TOT / KSPLIT)   // 1024
#define BK 32

typedef short  short8  __attribute__((ext_vector_type(8)));
typedef float  floatx4 __attribute__((ext_vector_type(4)));
typedef int    intx4   __attribute__((ext_vector_type(4)));

union S8U { intx4 i; short8 s; };

// ws layout: [0, 4MB)        bf16 table, FRAGMENT-MAJOR: [c=16][kb=256][lane=64][8 shorts]
//            [4MB, 4MB+32KB) int rowsum[8192]
#define WS_RS_OFF (4u * 1024u * 1024u)

__device__ __forceinline__ unsigned int bf16_rne(float f) {
    unsigned int u = __float_as_uint(f);
    u += 0x7fffu + ((u >> 16) & 1u);
    return u >> 16;
}

// ---- zero d_out (8 MB) and rowsum (32 KB) ----
__global__ __launch_bounds__(256) void zero_kernel(float* __restrict__ out, int* __restrict__ rs) {
    int b = blockIdx.x;
    if (b < 2048) {
        floatx4 z = {0.f, 0.f, 0.f, 0.f};
        *(floatx4*)(out + ((size_t)b * 256 + threadIdx.x) * 4) = z;
    } else {
        intx4 z = {0, 0, 0, 0};
        *(intx4*)(rs + ((size_t)(b - 2048) * 256 + threadIdx.x) * 4) = z;
    }
}

// ---- emb [8192][256] fp32 -> fragment-major bf16 table, scaled by sqrt(D)=16 ----
// wsBf[((c*256 + kb)*64 + lane)*8 + jj] = bf16( emb[kb*32 + (lane>>4)*8 + jj][c*16 + (lane&15)] * 16 )
__global__ __launch_bounds__(256) void prep_kernel(const float* __restrict__ emb,
                                                   unsigned short* __restrict__ wsBf) {
    int gid = blockIdx.x * 256 + threadIdx.x;       // 256K threads
    int l  = gid & 63;
    int kb = (gid >> 6) & 255;
    int c  = gid >> 14;
    int d  = c * 16 + (l & 15);
    int v0 = kb * 32 + (l >> 4) * 8;
    const float* src = emb + (size_t)v0 * D_DIM + d;
    intx4 q;
#pragma unroll
    for (int p = 0; p < 4; ++p) {
        unsigned int u0 = bf16_rne(src[(size_t)(2 * p) * D_DIM] * 16.0f);
        unsigned int u1 = bf16_rne(src[(size_t)(2 * p + 1) * D_DIM] * 16.0f);
        q[p] = (int)(u0 | (u1 << 16));
    }
    *(intx4*)(wsBf + (size_t)gid * 8) = q;
}

// ---- main GEMM: grid (128 m-blocks, KSPLIT=8), 256 threads = 4 waves, NO LDS, NO barriers ----
__global__ __launch_bounds__(256) void gemm_kernel(const int* __restrict__ x,
                                                   const unsigned short* __restrict__ wsBf,
                                                   float* __restrict__ out,
                                                   int* __restrict__ rs) {
    const int m0   = blockIdx.x * 64;
    const int kbeg = blockIdx.y * KCHUNK;
    const int t    = threadIdx.x;
    const int wave = t >> 6, lane = t & 63;
    const int quad = lane >> 4, rl = lane & 15;
    const int n0   = wave * 64;                 // wave's 64-column slice

    floatx4 acc[4][4];
#pragma unroll
    for (int i = 0; i < 4; ++i)
#pragma unroll
        for (int j = 0; j < 4; ++j) acc[i][j] = (floatx4){0.f, 0.f, 0.f, 0.f};

    int rp[4] = {0, 0, 0, 0};                   // packed row-sum pairs (wave 0 only)

    // A: lane (rl,quad) loads exactly its fragment: row m0+i*16+rl, k = kbeg+kk+quad*8 .. +7.
    // Quads 0..3 of a row cover one full 128-B line -> no over-fetch vs coalesced.
    const int* abase = x + (size_t)(m0 + rl) * K_TOT + kbeg + quad * 8;
    // B: fragment-major, wave streams contiguous 1-KB chunks per fragment
    const unsigned short* bbase = wsBf + ((size_t)(n0 >> 4) * 256) * 512 + (size_t)lane * 8;

#pragma unroll 2
    for (int kk = 0; kk < KCHUNK; kk += BK) {
        const int kb = (kbeg + kk) >> 5;        // k-block index in the fragment-major table

        short8 bf[4];
#pragma unroll
        for (int j = 0; j < 4; ++j)
            bf[j] = ((const S8U*)(bbase + ((size_t)j * 256 + kb) * 512))->s;

        short8 af[4];
#pragma unroll
        for (int i = 0; i < 4; ++i) {
            const int* p = abase + (size_t)(i * 16) * K_TOT + kk;
            intx4 a0 = *(const intx4*)p;
            intx4 a1 = *(const intx4*)(p + 4);
            // pack 0/1 pairs, then *0x3F80 turns each half into bf16 1.0/0.0
            int p0 = a0[0] | (a0[1] << 16);
            int p1 = a0[2] | (a0[3] << 16);
            int p2 = a1[0] | (a1[1] << 16);
            int p3 = a1[2] | (a1[3] << 16);
            if (wave == 0) rp[i] += p0 + p1 + p2 + p3;
            S8U u;
            u.i[0] = p0 * 0x3F80;
            u.i[1] = p1 * 0x3F80;
            u.i[2] = p2 * 0x3F80;
            u.i[3] = p3 * 0x3F80;
            af[i] = u.s;
        }

#pragma unroll
        for (int i = 0; i < 4; ++i)
#pragma unroll
            for (int j = 0; j < 4; ++j)
                acc[i][j] = __builtin_amdgcn_mfma_f32_16x16x32_bf16(af[i], bf[j], acc[i][j], 0, 0, 0);
    }

    // row-sum: lane holds counts for rows m0+i*16+rl over its quad k-slice; reduce across quads
    if (wave == 0) {
#pragma unroll
        for (int i = 0; i < 4; ++i) {
            int cnt = (rp[i] & 0xFFFF) + (rp[i] >> 16);
            cnt += __shfl_xor(cnt, 16);
            cnt += __shfl_xor(cnt, 32);
            if (quad == 0) atomicAdd(&rs[m0 + i * 16 + rl], cnt);
        }
    }

    // C/D layout: col = lane&15, row = quad*4 + reg (m89-verified). Atomic-accumulate K-partials.
#pragma unroll
    for (int i = 0; i < 4; ++i) {
#pragma unroll
        for (int j = 0; j < 4; ++j) {
            int col = n0 + j * 16 + rl;
#pragma unroll
            for (int r = 0; r < 4; ++r) {
                int row = m0 + i * 16 + quad * 4 + r;
                unsafeAtomicAdd(&out[(size_t)row * D_DIM + col], acc[i][j][r]);
            }
        }
    }
}

// ---- epilogue: out[m,:] += pos[m%1024,:] where rowsum[m] > 0 ----
__global__ __launch_bounds__(256) void epi_kernel(float* __restrict__ out,
                                                  const float* __restrict__ pos,
                                                  const int* __restrict__ rs) {
    int gid  = blockIdx.x * 256 + threadIdx.x;
    int base = gid * 4;                 // 4 floats per thread, stays within one row
    int row  = base >> 8;
    int col  = base & 255;
    if (rs[row] > 0) {
        int s = row & 1023;             // m = b*1024 + s
        floatx4 o = *(floatx4*)(out + base);
        floatx4 p = *(const floatx4*)(pos + (size_t)s * D_DIM + col);
        o += p;
        *(floatx4*)(out + base) = o;
    }
}

extern "C" void kernel_launch(void* const* d_in, const int* in_sizes, int n_in,
                              void* d_out, int out_size, void* d_ws, size_t ws_size,
                              hipStream_t stream) {
    const int*   x   = (const int*)d_in[0];     // [8,1024,8192] int32
    const float* emb = (const float*)d_in[1];   // [8192,256] fp32
    const float* pos = (const float*)d_in[2];   // [1,1024,256] fp32
    float*       out = (float*)d_out;           // [8,1024,256] fp32

    unsigned short* wsBf = (unsigned short*)d_ws;              // 4 MB fragment-major bf16 table
    int*            rs   = (int*)((char*)d_ws + WS_RS_OFF);    // 32 KB row sums

    zero_kernel<<<dim3(2056), dim3(256), 0, stream>>>(out, rs);
    prep_kernel<<<dim3(1024), dim3(256), 0, stream>>>(emb, wsBf);
    gemm_kernel<<<dim3(128, KSPLIT), dim3(256), 0, stream>>>(x, wsBf, out, rs);
    epi_kernel<<<dim3(2048), dim3(256), 0, stream>>>(out, pos, rs);
}

// Round 3
// 421.749 us; speedup vs baseline: 1.1272x; 1.1272x over previous
//
#include <hip/hip_runtime.h>
#include <stdint.h>

// Problem: B=8, S=1024, V=8192, D=256. out[b,s,:] = (x[b,s,:] @ E)*16 + pos[s,:]*any(x[b,s,:])
// GEMM M=8192 K=8192 N=256, A=x (0/1 int32, streamed 256 MB), B=emb (bf16 table in ws).
// R3: no atomics (K-partials to ws + reduce kernel), A staged via global_load_lds dbuf
//     with XOR-swizzled layout (coalesced global, conflict-free ds_read_b128).

#define K_TOT 8192
#define D_DIM 256
#define KSPLIT 4
#define KCHUNK (K_TOT / KSPLIT)   // 2048
#define BK 64                     // ints of k per tile
#define TROWS 32                  // rows per block
#define NTILES (KCHUNK / BK)      // 32
#define PART_STRIDE (8192u * 256u)  // floats per partial

typedef short  short8  __attribute__((ext_vector_type(8)));
typedef float  floatx4 __attribute__((ext_vector_type(4)));
typedef int    intx4   __attribute__((ext_vector_type(4)));

union S8U { intx4 i; short8 s; };

// ws layout: [0,4MB) bf16 B-table [c=16][kb=256][lane=64][8]
//            [4MB, 36MB) fp32 partials [KSPLIT][8192][256]
//            [36MB, +4*32KB) int rs_part [KSPLIT][8192]
#define WS_PART_OFF (4u * 1024u * 1024u)
#define WS_RS_OFF   (36u * 1024u * 1024u)

__device__ __forceinline__ unsigned int bf16_rne(float f) {
    unsigned int u = __float_as_uint(f);
    u += 0x7fffu + ((u >> 16) & 1u);
    return u >> 16;
}

__device__ __forceinline__ void load_lds16(const int* g, int* l) {
    __builtin_amdgcn_global_load_lds((const __attribute__((address_space(1))) unsigned int*)g,
                                     (__attribute__((address_space(3))) unsigned int*)l,
                                     16, 0, 0);
}

// ---- emb [8192][256] fp32 -> fragment-major bf16 table, scaled by sqrt(D)=16 ----
// wsBf[((c*256+kb)*64+l)*8+jj] = bf16(emb[kb*32+(l>>4)*8+jj][c*16+(l&15)] * 16)
__global__ __launch_bounds__(256) void prep_kernel(const float* __restrict__ emb,
                                                   unsigned short* __restrict__ wsBf) {
    int gid = blockIdx.x * 256 + threadIdx.x;
    int l  = gid & 63;
    int kb = (gid >> 6) & 255;
    int c  = gid >> 14;
    int d  = c * 16 + (l & 15);
    int v0 = kb * 32 + (l >> 4) * 8;
    const float* src = emb + (size_t)v0 * D_DIM + d;
    intx4 q;
#pragma unroll
    for (int p = 0; p < 4; ++p) {
        unsigned int u0 = bf16_rne(src[(size_t)(2 * p) * D_DIM] * 16.0f);
        unsigned int u1 = bf16_rne(src[(size_t)(2 * p + 1) * D_DIM] * 16.0f);
        q[p] = (int)(u0 | (u1 << 16));
    }
    *(intx4*)(wsBf + (size_t)gid * 8) = q;
}

// ---- GEMM: grid (256 m-blocks of 32 rows, KSPLIT), 256 thr = 4 waves (64-col slices) ----
// LDS tile layout: 16B slot s (s=0..511): row = s>>4, k16 = (s&15) ^ (row&7)  [XOR swizzle]
__global__ __launch_bounds__(256) void gemm_kernel(const int* __restrict__ x,
                                                   const unsigned short* __restrict__ wsBf,
                                                   float* __restrict__ part,
                                                   int* __restrict__ rsp) {
    __shared__ int Al[2][2048];    // 2 x 8KB (32 rows x 64 ints)

    const int m0   = blockIdx.x * TROWS;
    const int kidx = blockIdx.y;
    const int kbeg = kidx * KCHUNK;
    const int t    = threadIdx.x;
    const int wave = t >> 6, lane = t & 63;
    const int quad = lane >> 4, rl = lane & 15;
    const int sx   = rl & 7;                    // read-side swizzle key

    // staging: round 0 slot = t (rows 0..15), round 1 slot = 256+t (rows 16..31, same kof)
    const int row0 = t >> 4;
    const int kof  = (t & 15) ^ (row0 & 7);
    const int* g0 = x + (size_t)(m0 + row0) * K_TOT + kbeg + kof * 4;
    const int* g1 = g0 + (size_t)16 * K_TOT;

    floatx4 acc[2][4];
#pragma unroll
    for (int i = 0; i < 2; ++i)
#pragma unroll
        for (int j = 0; j < 4; ++j) acc[i][j] = (floatx4){0.f, 0.f, 0.f, 0.f};
    int rp[2] = {0, 0};

    const int kbase = kidx * (KCHUNK / 32);     // global 32-int k-block base

    // prologue: stage tile 0 into buf 0
    load_lds16(g0, &Al[0][t * 4]);
    load_lds16(g1, &Al[0][1024 + t * 4]);

    for (int tl = 0; tl < NTILES; ++tl) {
        __syncthreads();                         // buf[tl&1] ready; prior readers done
        if (tl + 1 < NTILES) {
            const int* ga = g0 + (tl + 1) * BK;
            const int* gb = g1 + (tl + 1) * BK;
            int* dst = &Al[(tl + 1) & 1][0];
            load_lds16(ga, dst + t * 4);
            load_lds16(gb, dst + 1024 + t * 4);
        }
        const int* buf = &Al[tl & 1][0];

#pragma unroll
        for (int s = 0; s < 2; ++s) {            // two k32 steps per tile
            const int kb = kbase + tl * 2 + s;

            short8 bf[4];
#pragma unroll
            for (int j = 0; j < 4; ++j)
                bf[j] = ((const S8U*)(wsBf + ((size_t)((wave * 4 + j) * 256 + kb) * 64 + lane) * 8))->s;

            short8 af[2];
#pragma unroll
            for (int i = 0; i < 2; ++i) {
                int ka = (s * 8 + quad * 2) ^ sx;        // slot of ints k..k+3
                int kc = (s * 8 + quad * 2 + 1) ^ sx;    // slot of ints k+4..k+7
                int rowb = (i * 16 + rl) * 16;
                intx4 v0 = *(const intx4*)(buf + (rowb + ka) * 4);
                intx4 v1 = *(const intx4*)(buf + (rowb + kc) * 4);
                int p0 = v0[0] | (v0[1] << 16);
                int p1 = v0[2] | (v0[3] << 16);
                int p2 = v1[0] | (v1[1] << 16);
                int p3 = v1[2] | (v1[3] << 16);
                if (wave == 0) rp[i] += p0 + p1 + p2 + p3;
                S8U u;
                u.i[0] = p0 * 0x3F80;
                u.i[1] = p1 * 0x3F80;
                u.i[2] = p2 * 0x3F80;
                u.i[3] = p3 * 0x3F80;
                af[i] = u.s;
            }

#pragma unroll
            for (int i = 0; i < 2; ++i)
#pragma unroll
                for (int j = 0; j < 4; ++j)
                    acc[i][j] = __builtin_amdgcn_mfma_f32_16x16x32_bf16(af[i], bf[j], acc[i][j], 0, 0, 0);
        }
    }

    // row-sums (wave 0 saw every A element): reduce quads, store per-block (no atomics)
    if (wave == 0) {
#pragma unroll
        for (int i = 0; i < 2; ++i) {
            int cnt = (rp[i] & 0xFFFF) + ((unsigned)rp[i] >> 16);
            cnt += __shfl_xor(cnt, 16);
            cnt += __shfl_xor(cnt, 32);
            if (quad == 0) rsp[(size_t)kidx * 8192 + m0 + i * 16 + rl] = cnt;
        }
    }

    // partial store: C/D layout col=lane&15, row=quad*4+reg (m89-verified)
    float* pk = part + (size_t)kidx * PART_STRIDE;
#pragma unroll
    for (int i = 0; i < 2; ++i) {
#pragma unroll
        for (int j = 0; j < 4; ++j) {
            int col = wave * 64 + j * 16 + rl;
#pragma unroll
            for (int r = 0; r < 4; ++r) {
                int row = m0 + i * 16 + quad * 4 + r;
                pk[(size_t)row * D_DIM + col] = acc[i][j][r];
            }
        }
    }
}

// ---- reduce: out = sum_k part[k] + pos * (sum_k rs[k] > 0) ----
__global__ __launch_bounds__(256) void reduce_kernel(const float* __restrict__ part,
                                                     const int* __restrict__ rsp,
                                                     const float* __restrict__ pos,
                                                     float* __restrict__ out) {
    int gid = blockIdx.x * 256 + threadIdx.x;    // 512K threads, 4 floats each
    size_t base = (size_t)gid * 4;
    int row = gid >> 6;
    floatx4 a = *(const floatx4*)(part + base);
    a += *(const floatx4*)(part + 1 * (size_t)PART_STRIDE + base);
    a += *(const floatx4*)(part + 2 * (size_t)PART_STRIDE + base);
    a += *(const floatx4*)(part + 3 * (size_t)PART_STRIDE + base);
    int rsum = rsp[row] + rsp[8192 + row] + rsp[16384 + row] + rsp[24576 + row];
    if (rsum > 0) {
        int s = row & 1023;
        int col = (gid & 63) * 4;
        a += *(const floatx4*)(pos + (size_t)s * D_DIM + col);
    }
    *(floatx4*)(out + base) = a;
}

extern "C" void kernel_launch(void* const* d_in, const int* in_sizes, int n_in,
                              void* d_out, int out_size, void* d_ws, size_t ws_size,
                              hipStream_t stream) {
    const int*   x   = (const int*)d_in[0];     // [8,1024,8192] int32
    const float* emb = (const float*)d_in[1];   // [8192,256] fp32
    const float* pos = (const float*)d_in[2];   // [1,1024,256] fp32
    float*       out = (float*)d_out;           // [8,1024,256] fp32

    unsigned short* wsBf = (unsigned short*)d_ws;
    float*          part = (float*)((char*)d_ws + WS_PART_OFF);
    int*            rsp  = (int*)((char*)d_ws + WS_RS_OFF);

    prep_kernel<<<dim3(1024), dim3(256), 0, stream>>>(emb, wsBf);
    gemm_kernel<<<dim3(256, KSPLIT), dim3(256), 0, stream>>>(x, wsBf, part, rsp);
    reduce_kernel<<<dim3(2048), dim3(256), 0, stream>>>(part, rsp, pos, out);
}